// Round 4
// baseline (3965.495 us; speedup 1.0000x reference)
//
#include <hip/hip_runtime.h>
#include <math.h>

#define NUM_TOKENS 16384
#define HIDDEN 2048
#define NUM_EXPERTS 64

// out layout (fp32 flat): [0,32768) weights [t][2]; [32768,65536) indices as float; [65536] aux
#define IDX_OFF 32768
#define AUX_OFF 65536

#define KSLICE 256          // k-depth per wave (8 waves cover HIDDEN=2048)
#define SUBK 32             // W rows per staged sub-chunk (8 KB)
#define NSUB (KSLICE / SUBK)

__global__ __launch_bounds__(512, 2) void router_kernel(
    const float* __restrict__ x, const float* __restrict__ Wg,
    float* __restrict__ out, float* __restrict__ ws)
{
    // 8 waves x double-buffered [SUBK][64] W tiles = 32768 floats = 128 KB.
    // Reduction buffers are overlaid on this after a barrier.
    __shared__ float smem[8 * 2 * SUBK * NUM_EXPERTS];

    const int tid  = threadIdx.x;
    const int w    = tid >> 6;         // wave 0..7 = k-slice
    const int lane = tid & 63;         // lane = token-within-block
    const int token = blockIdx.x * 64 + lane;
    const int k0 = w * KSLICE;

    float* wbuf = &smem[w * (2 * SUBK * NUM_EXPERTS)];   // wave-private 16 KB

    float C[64];
    #pragma unroll
    for (int e = 0; e < 64; ++e) C[e] = 0.f;

    const float4* xr4 = reinterpret_cast<const float4*>(x + (size_t)token * HIDDEN + k0);
    const float4* Wg4 = reinterpret_cast<const float4*>(Wg);

    // prologue: stage sub-chunk 0 into half 0 (coalesced 8 KB per wave)
    {
        const size_t base = (size_t)k0 * (NUM_EXPERTS / 4);
        #pragma unroll
        for (int j = 0; j < 8; ++j) {
            float4 v = Wg4[base + (size_t)j * 64 + lane];
            *reinterpret_cast<float4*>(wbuf + ((size_t)j * 64 + lane) * 4) = v;
        }
    }

    for (int s = 0; s < NSUB; ++s) {
        const int cur = s & 1;

        // issue next W sub-chunk loads early (covered by ~4096 cy of FMA)
        float4 wreg[8];
        if (s + 1 < NSUB) {
            const size_t base = (size_t)(k0 + (s + 1) * SUBK) * (NUM_EXPERTS / 4);
            #pragma unroll
            for (int j = 0; j < 8; ++j) wreg[j] = Wg4[base + (size_t)j * 64 + lane];
        }
        // x for this sub-chunk: 32 k = 8 float4 per lane
        float4 xv[8];
        #pragma unroll
        for (int j = 0; j < 8; ++j) xv[j] = xr4[s * 8 + j];

        const float* wb = wbuf + cur * (SUBK * NUM_EXPERTS);
        #pragma unroll
        for (int j = 0; j < 8; ++j) {
            const float xq[4] = {xv[j].x, xv[j].y, xv[j].z, xv[j].w};
            #pragma unroll
            for (int q = 0; q < 4; ++q) {
                const float* wrow = wb + (j * 4 + q) * NUM_EXPERTS;  // uniform addr -> broadcast
                #pragma unroll
                for (int e4 = 0; e4 < 16; ++e4) {
                    const float4 wv = *reinterpret_cast<const float4*>(wrow + e4 * 4);
                    C[e4*4+0] = fmaf(xq[q], wv.x, C[e4*4+0]);
                    C[e4*4+1] = fmaf(xq[q], wv.y, C[e4*4+1]);
                    C[e4*4+2] = fmaf(xq[q], wv.z, C[e4*4+2]);
                    C[e4*4+3] = fmaf(xq[q], wv.w, C[e4*4+3]);
                }
            }
        }

        // write next sub-chunk into the other half (wave-private; lgkmcnt orders)
        if (s + 1 < NSUB) {
            float* wn = wbuf + (cur ^ 1) * (SUBK * NUM_EXPERTS);
            #pragma unroll
            for (int j = 0; j < 8; ++j)
                *reinterpret_cast<float4*>(wn + ((size_t)j * 64 + lane) * 4) = wreg[j];
        }
    }

    __syncthreads();   // compute done everywhere; safe to overlay reduction buffers

    // reduction overlay: rbuf[4][64][68] floats + top1s[64] ints
    float* rbuf = smem;
    int* top1s = reinterpret_cast<int*>(smem + 4 * 64 * 68);

    #define WBUF(b) { _Pragma("unroll") for (int e4 = 0; e4 < 16; ++e4) { \
        float4 v; v.x = C[e4*4+0]; v.y = C[e4*4+1]; v.z = C[e4*4+2]; v.w = C[e4*4+3]; \
        *reinterpret_cast<float4*>(&rbuf[(b) * 4352 + lane * 68 + e4 * 4]) = v; } }
    #define ABUF(b) { _Pragma("unroll") for (int e4 = 0; e4 < 16; ++e4) { \
        const float4 v = *reinterpret_cast<const float4*>(&rbuf[(b) * 4352 + lane * 68 + e4 * 4]); \
        C[e4*4+0] += v.x; C[e4*4+1] += v.y; C[e4*4+2] += v.z; C[e4*4+3] += v.w; } }

    // 3-round tree: 8 partials -> wave 0
    if (w >= 4) WBUF(w - 4);
    __syncthreads();
    if (w < 4) ABUF(w);
    __syncthreads();
    if (w == 2 || w == 3) WBUF(w - 2);
    __syncthreads();
    if (w < 2) ABUF(w);
    __syncthreads();
    if (w == 1) WBUF(0);
    __syncthreads();

    if (w == 0) {
        ABUF(0);   // full logits for this token, lane-local in C[64]

        float m = C[0];
        #pragma unroll
        for (int e = 1; e < 64; ++e) m = fmaxf(m, C[e]);
        float Z = 0.f;
        #pragma unroll
        for (int e = 0; e < 64; ++e) { C[e] = expf(C[e] - m); Z += C[e]; }
        const float rz = 1.f / Z;

        float v1 = -1.f, v2 = -1.f; int i1 = 0, i2 = 0;
        #pragma unroll
        for (int e = 0; e < 64; ++e) {
            const float p = C[e] * rz;
            C[e] = p;
            if (p > v1)      { v2 = v1; i2 = i1; v1 = p; i1 = e; }
            else if (p > v2) { v2 = p;  i2 = e; }
        }

        const float s = v1 + v2 + 1e-9f;
        float2 wo; wo.x = v1 / s; wo.y = v2 / s;
        *reinterpret_cast<float2*>(&out[(size_t)token * 2]) = wo;
        float2 io; io.x = (float)i1; io.y = (float)i2;
        *reinterpret_cast<float2*>(&out[IDX_OFF + (size_t)token * 2]) = io;

        WBUF(0);             // stash probs for aux column-sums
        top1s[lane] = i1;
    }
    __syncthreads();

    if (w == 1) {            // lane = expert
        float sp = 0.f;
        #pragma unroll 8
        for (int t = 0; t < 64; ++t) sp += rbuf[t * 68 + lane];
        float cnt = 0.f;
        #pragma unroll 8
        for (int t = 0; t < 64; ++t) cnt += (top1s[t] == lane) ? 1.f : 0.f;
        ws[(size_t)blockIdx.x * 128 + lane]      = sp;
        ws[(size_t)blockIdx.x * 128 + 64 + lane] = cnt;
    }
}

__global__ __launch_bounds__(64) void finalize_kernel(
    const float* __restrict__ ws, float* __restrict__ out)
{
    const int e = threadIdx.x;  // 0..63
    float sp = 0.f, sc = 0.f;
    for (int b = 0; b < NUM_TOKENS / 64; ++b) {
        sp += ws[(size_t)b * 128 + e];
        sc += ws[(size_t)b * 128 + 64 + e];
    }
    float val = (sc * (1.0f / NUM_TOKENS)) * (sp * (1.0f / NUM_TOKENS));
    #pragma unroll
    for (int off = 32; off >= 1; off >>= 1) val += __shfl_xor(val, off);
    if (e == 0) out[AUX_OFF] = (float)NUM_EXPERTS * val;
}

extern "C" void kernel_launch(void* const* d_in, const int* in_sizes, int n_in,
                              void* d_out, int out_size, void* d_ws, size_t ws_size,
                              hipStream_t stream) {
    const float* x  = (const float*)d_in[0];
    const float* Wg = (const float*)d_in[1];
    float* out = (float*)d_out;
    float* ws  = (float*)d_ws;

    router_kernel<<<NUM_TOKENS / 64, 512, 0, stream>>>(x, Wg, out, ws);
    finalize_kernel<<<1, 64, 0, stream>>>(ws, out);
}

// Round 5
// 113.440 us; speedup vs baseline: 34.9567x; 34.9567x over previous
//
#include <hip/hip_runtime.h>
#include <math.h>

#define NUM_TOKENS 16384
#define HIDDEN 2048
#define NUM_EXPERTS 64

// out layout (fp32 flat): [0,32768) weights [t][2]; [32768,65536) indices as float; [65536] aux
#define IDX_OFF 32768
#define AUX_OFF 65536

// ---- split-K config ----
#define NSLICE 8
#define KSL (HIDDEN / NSLICE)              // 256 k per slice
#define TB 512                              // tokens per gemm block
#define NTB (NUM_TOKENS / TB)               // 32 token blocks
#define PART_FLOATS ((size_t)NSLICE * NUM_TOKENS * NUM_EXPERTS)   // 8,388,608 floats
#define WS_NEEDED ((PART_FLOATS + (size_t)(NUM_TOKENS / 64) * 128) * sizeof(float))

// ================= split-K path =================

// Grid 256 = 32 token-blocks x 8 slices; 8 waves/block all share ONE k-window
// so the scalar cache gets 8x reuse on W rows (R3's miss-serialization fix).
__global__ __launch_bounds__(512, 2) void gemm_kernel(
    const float* __restrict__ x, const float* __restrict__ Wg,
    float* __restrict__ ws)
{
    const int tid = threadIdx.x;
    const int tb  = blockIdx.x & (NTB - 1);
    const int sl  = blockIdx.x >> 5;               // 0..7
    const int token = tb * TB + tid;
    const int k0 = sl * KSL;                       // scalar (SGPR)

    float C[64];
    #pragma unroll
    for (int e = 0; e < 64; ++e) C[e] = 0.f;

    const float4* xr = reinterpret_cast<const float4*>(x + (size_t)token * HIDDEN + k0);

    // R3's proven no-spill inner loop shape (VGPR ~52)
    float4 cur = xr[0];
    for (int c = 0; c < KSL / 4; ++c) {            // 64 iterations
        float4 nxt = xr[(c + 1) & (KSL / 4 - 1)];
        const float xv[4] = {cur.x, cur.y, cur.z, cur.w};
        #pragma unroll
        for (int q = 0; q < 4; ++q) {
            const int k = k0 + c * 4 + q;          // fully scalar
            const float* __restrict__ wrow = Wg + (size_t)k * NUM_EXPERTS;
            #pragma unroll
            for (int e = 0; e < 64; ++e)
                C[e] = fmaf(xv[q], wrow[e], C[e]); // v_fmac vdst, s_w, v_x
        }
        cur = nxt;
    }

    // partial logits -> ws[sl][token][64], 256 B/lane contiguous
    float* pr = ws + ((size_t)sl * NUM_TOKENS + token) * NUM_EXPERTS;
    #pragma unroll
    for (int e4 = 0; e4 < 16; ++e4) {
        float4 v; v.x = C[e4*4+0]; v.y = C[e4*4+1]; v.z = C[e4*4+2]; v.w = C[e4*4+3];
        *reinterpret_cast<float4*>(pr + e4 * 4) = v;
    }
}

// Grid 256 x 64 threads: lane = token. Sum 8 slices, softmax, top2, aux partials.
__global__ __launch_bounds__(64) void reduce_kernel(
    const float* __restrict__ ws, float* __restrict__ out, float* __restrict__ ws_aux)
{
    __shared__ float pbuf[64][68];
    __shared__ int top1s[64];

    const int lane = threadIdx.x;
    const int token = blockIdx.x * 64 + lane;

    float C[64];
    #pragma unroll
    for (int e = 0; e < 64; ++e) C[e] = 0.f;

    for (int s = 0; s < NSLICE; ++s) {
        const float* pr = ws + ((size_t)s * NUM_TOKENS + token) * NUM_EXPERTS;
        #pragma unroll
        for (int e4 = 0; e4 < 16; ++e4) {
            const float4 v = *reinterpret_cast<const float4*>(pr + e4 * 4);
            C[e4*4+0] += v.x; C[e4*4+1] += v.y; C[e4*4+2] += v.z; C[e4*4+3] += v.w;
        }
    }

    float m = C[0];
    #pragma unroll
    for (int e = 1; e < 64; ++e) m = fmaxf(m, C[e]);
    float Z = 0.f;
    #pragma unroll
    for (int e = 0; e < 64; ++e) { C[e] = expf(C[e] - m); Z += C[e]; }
    const float rz = 1.f / Z;

    float v1 = -1.f, v2 = -1.f; int i1 = 0, i2 = 0;
    #pragma unroll
    for (int e = 0; e < 64; ++e) {
        const float p = C[e] * rz;
        C[e] = p;
        if (p > v1)      { v2 = v1; i2 = i1; v1 = p; i1 = e; }
        else if (p > v2) { v2 = p;  i2 = e; }
    }

    const float s = v1 + v2 + 1e-9f;
    float2 wo; wo.x = v1 / s; wo.y = v2 / s;
    *reinterpret_cast<float2*>(&out[(size_t)token * 2]) = wo;
    float2 io; io.x = (float)i1; io.y = (float)i2;
    *reinterpret_cast<float2*>(&out[IDX_OFF + (size_t)token * 2]) = io;

    #pragma unroll
    for (int e4 = 0; e4 < 16; ++e4)
        *reinterpret_cast<float4*>(&pbuf[lane][e4 * 4]) =
            make_float4(C[e4*4+0], C[e4*4+1], C[e4*4+2], C[e4*4+3]);
    top1s[lane] = i1;
    __syncthreads();

    float sp = 0.f;
    #pragma unroll 8
    for (int t = 0; t < 64; ++t) sp += pbuf[t][lane];
    float cnt = 0.f;
    #pragma unroll 8
    for (int t = 0; t < 64; ++t) cnt += (top1s[t] == lane) ? 1.f : 0.f;
    ws_aux[(size_t)blockIdx.x * 128 + lane]      = sp;
    ws_aux[(size_t)blockIdx.x * 128 + 64 + lane] = cnt;
}

// ================= fallback path (R3 verbatim, known 104 us) =================

#define KSLICE 256

__global__ __launch_bounds__(512, 2) void router_fallback(
    const float* __restrict__ x, const float* __restrict__ Wg,
    float* __restrict__ out, float* __restrict__ ws)
{
    __shared__ float buf[4][64][68];
    __shared__ int top1s[64];

    const int tid  = threadIdx.x;
    const int w    = tid >> 6;
    const int lane = tid & 63;
    const int token = blockIdx.x * 64 + lane;
    const int k0 = __builtin_amdgcn_readfirstlane(w) * KSLICE;

    float C[64];
    #pragma unroll
    for (int e = 0; e < 64; ++e) C[e] = 0.f;

    const float4* xr = reinterpret_cast<const float4*>(x + (size_t)token * HIDDEN + k0);

    float4 cur = xr[0];
    for (int c = 0; c < KSLICE / 4; ++c) {
        float4 nxt = xr[(c + 1) & (KSLICE / 4 - 1)];
        const float xv[4] = {cur.x, cur.y, cur.z, cur.w};
        #pragma unroll
        for (int q = 0; q < 4; ++q) {
            const int k = k0 + c * 4 + q;
            const float* __restrict__ wrow = Wg + (size_t)k * NUM_EXPERTS;
            #pragma unroll
            for (int e = 0; e < 64; ++e)
                C[e] = fmaf(xv[q], wrow[e], C[e]);
        }
        cur = nxt;
    }

    #define WBUF(b) { _Pragma("unroll") for (int e4 = 0; e4 < 16; ++e4) { \
        float4 v; v.x = C[e4*4+0]; v.y = C[e4*4+1]; v.z = C[e4*4+2]; v.w = C[e4*4+3]; \
        *reinterpret_cast<float4*>(&buf[b][lane][e4*4]) = v; } }
    #define ABUF(b) { _Pragma("unroll") for (int e4 = 0; e4 < 16; ++e4) { \
        const float4 v = *reinterpret_cast<const float4*>(&buf[b][lane][e4*4]); \
        C[e4*4+0] += v.x; C[e4*4+1] += v.y; C[e4*4+2] += v.z; C[e4*4+3] += v.w; } }

    if (w >= 4) WBUF(w - 4);
    __syncthreads();
    if (w < 4) ABUF(w);
    __syncthreads();
    if (w == 2 || w == 3) WBUF(w - 2);
    __syncthreads();
    if (w < 2) ABUF(w);
    __syncthreads();
    if (w == 1) WBUF(0);
    __syncthreads();

    if (w == 0) {
        ABUF(0);
        float m = C[0];
        #pragma unroll
        for (int e = 1; e < 64; ++e) m = fmaxf(m, C[e]);
        float Z = 0.f;
        #pragma unroll
        for (int e = 0; e < 64; ++e) { C[e] = expf(C[e] - m); Z += C[e]; }
        const float rz = 1.f / Z;

        float v1 = -1.f, v2 = -1.f; int i1 = 0, i2 = 0;
        #pragma unroll
        for (int e = 0; e < 64; ++e) {
            const float p = C[e] * rz;
            C[e] = p;
            if (p > v1)      { v2 = v1; i2 = i1; v1 = p; i1 = e; }
            else if (p > v2) { v2 = p;  i2 = e; }
        }
        const float s = v1 + v2 + 1e-9f;
        float2 wo; wo.x = v1 / s; wo.y = v2 / s;
        *reinterpret_cast<float2*>(&out[(size_t)token * 2]) = wo;
        float2 io; io.x = (float)i1; io.y = (float)i2;
        *reinterpret_cast<float2*>(&out[IDX_OFF + (size_t)token * 2]) = io;
        WBUF(0);
        top1s[lane] = i1;
    }
    __syncthreads();

    if (w == 1) {
        float sp = 0.f;
        #pragma unroll 8
        for (int t = 0; t < 64; ++t) sp += buf[0][t][lane];
        float cnt = 0.f;
        #pragma unroll 8
        for (int t = 0; t < 64; ++t) cnt += (top1s[t] == lane) ? 1.f : 0.f;
        ws[(size_t)blockIdx.x * 128 + lane]      = sp;
        ws[(size_t)blockIdx.x * 128 + 64 + lane] = cnt;
    }
}

// shared finalize: ws_aux is [NUM_TOKENS/64][128] partials
__global__ __launch_bounds__(64) void finalize_kernel(
    const float* __restrict__ ws_aux, float* __restrict__ out)
{
    const int e = threadIdx.x;
    float sp = 0.f, sc = 0.f;
    for (int b = 0; b < NUM_TOKENS / 64; ++b) {
        sp += ws_aux[(size_t)b * 128 + e];
        sc += ws_aux[(size_t)b * 128 + 64 + e];
    }
    float val = (sc * (1.0f / NUM_TOKENS)) * (sp * (1.0f / NUM_TOKENS));
    #pragma unroll
    for (int off = 32; off >= 1; off >>= 1) val += __shfl_xor(val, off);
    if (e == 0) out[AUX_OFF] = (float)NUM_EXPERTS * val;
}

extern "C" void kernel_launch(void* const* d_in, const int* in_sizes, int n_in,
                              void* d_out, int out_size, void* d_ws, size_t ws_size,
                              hipStream_t stream) {
    const float* x  = (const float*)d_in[0];
    const float* Wg = (const float*)d_in[1];
    float* out = (float*)d_out;
    float* ws  = (float*)d_ws;

    if (ws_size >= WS_NEEDED) {
        float* ws_aux = ws + PART_FLOATS;
        gemm_kernel<<<NTB * NSLICE, 512, 0, stream>>>(x, Wg, ws);
        reduce_kernel<<<NUM_TOKENS / 64, 64, 0, stream>>>(ws, out, ws_aux);
        finalize_kernel<<<1, 64, 0, stream>>>(ws_aux, out);
    } else {
        router_fallback<<<NUM_TOKENS / 64, 512, 0, stream>>>(x, Wg, out, ws);
        finalize_kernel<<<1, 64, 0, stream>>>(ws, out);
    }
}